// Round 6
// baseline (100.807 us; speedup 1.0000x reference)
//
#include <hip/hip_runtime.h>
#include <math.h>

#define NN 96
#define DD 512
#define PP 9120          // NN*(NN-1) ordered pairs
#define NUP 4560         // NN*(NN-1)/2 unordered pairs
#define EPSF 1e-8f
#define INV_TEMP 100.0f
#define LOG2E 1.4426950408889634f
#define RP 4             // unordered pairs per lse block (-> 8 LSE outputs)
#define NTASK (2*PP)     // 18240 LSE outputs total
#define NBLK (2*NUP/RP)  // 2280 blocks
#define CBASE (NUP/RP)   // 1140: first block handling column tasks

typedef float v2f __attribute__((ext_vector_type(2)));

// ws float-offset layout
#define OFF_PART  0        // 6 partial grams [zz][9216], zz = z*2+kslice; z=0:G z=1:Gt z=2:Gm
#define OFF_G     55296    // G  = txt*img^T   [96*96]
#define OFF_GT    64512    // GT = G^T         [96*96]
#define OFF_WT    73728    // wt[k][l] = 1/(||t_k-t_l||+eps), diag 0
#define OFF_WM    82944
#define OFF_WST   92160    // wt * log2e
#define OFF_WSM   101376   // wm * log2e
#define OFF_DIAG  110592   // diag[p], ordered p
#define OFF_WMAX  119712   // [0]=max wt, [1]=max wm (uint bits)
#define OFF_TAB   119714   // int table: q -> (i<<8)|j, i<j, q in [0,4560)

// Split-K tiled gram: 16x16 tile over a 256-dim K slice. grid (6,6,6).
// Also zeroes WMAX and d_out (replaces two memset dispatches).
__global__ __launch_bounds__(256) void gram_kernel(const float* __restrict__ txt,
                                                   const float* __restrict__ img,
                                                   float* __restrict__ ws,
                                                   float* __restrict__ out) {
    __shared__ float4 Al[16][65];
    __shared__ float4 Bl[16][65];
    if (blockIdx.x == 0 && blockIdx.y == 0 && blockIdx.z == 0 && threadIdx.x == 0) {
        ws[OFF_WMAX] = 0.f;
        ws[OFF_WMAX + 1] = 0.f;
        out[0] = 0.f;
    }
    int zz = blockIdx.z;
    int z = zz >> 1, ks = zz & 1;
    int a0 = blockIdx.x * 16, b0 = blockIdx.y * 16;
    const float* X = (z == 2) ? img : txt;
    const float* Y = (z == 0) ? img : ((z == 1) ? txt : img);
    const float4* Xp = (const float4*)X;     // row stride 128 float4
    const float4* Yp = (const float4*)Y;
    int tid = threadIdx.x;
    int r = tid >> 6, c = tid & 63;
    int kbase = ks * 64;
    #pragma unroll
    for (int rep = 0; rep < 4; ++rep) {
        int row = rep * 4 + r;
        Al[row][c] = Xp[(a0 + row) * 128 + kbase + c];
        Bl[row][c] = Yp[(b0 + row) * 128 + kbase + c];
    }
    __syncthreads();
    int al = tid >> 4, bl = tid & 15;
    float acc = 0.f;
    #pragma unroll 8
    for (int kk = 0; kk < 64; ++kk) {
        float4 av = Al[al][kk];
        float4 bv = Bl[bl][kk];
        acc += av.x*bv.x + av.y*bv.y + av.z*bv.z + av.w*bv.w;
    }
    ws[OFF_PART + zz * (NN*NN) + (a0 + al) * NN + (b0 + bl)] = acc;
}

// per (k,l): combine K-slice partials, G/GT, w grids, diag, Wmax, pair table
__global__ void pairs_kernel(float* __restrict__ ws) {
    int t = blockIdx.x * 256 + threadIdx.x;   // 36*256 = 9216 exactly
    int k = t / NN, l = t - k * NN;
    const float* P = ws + OFF_PART;
    #define RD(z, x) (P[(2*(z)) * (NN*NN) + (x)] + P[(2*(z)+1) * (NN*NN) + (x)])
    float gkl = RD(0, k*NN + l);
    float glk = RD(0, l*NN + k);
    ws[OFF_G  + t] = gkl;
    ws[OFF_GT + t] = glk;
    float wtv = 0.f, wmv = 0.f;
    if (k != l) {
        float nt2 = RD(1, k*NN+k) - 2.f*RD(1, k*NN+l) + RD(1, l*NN+l);
        float nm2 = RD(2, k*NN+k) - 2.f*RD(2, k*NN+l) + RD(2, l*NN+l);
        wtv = 1.f / (sqrtf(fmaxf(nt2, 0.f)) + EPSF);
        wmv = 1.f / (sqrtf(fmaxf(nm2, 0.f)) + EPSF);
        int p = k * 95 + l - (l > k ? 1 : 0);
        float gkk = RD(0, k*NN+k), gll = RD(0, l*NN+l);
        ws[OFF_DIAG + p] = INV_TEMP * wtv * wmv * (gkk - gkl - glk + gll);
        if (k < l) {
            int q = k * (2*NN - 1 - k) / 2 + (l - k - 1);
            ((int*)ws)[OFF_TAB + q] = (k << 8) | l;
        }
    }
    #undef RD
    ws[OFF_WT  + t] = wtv;
    ws[OFF_WM  + t] = wmv;
    ws[OFF_WST + t] = wtv * LOG2E;
    ws[OFF_WSM + t] = wmv * LOG2E;
    float mt = wtv, mm = wmv;
    #pragma unroll
    for (int off = 32; off > 0; off >>= 1) {
        mt = fmaxf(mt, __shfl_xor(mt, off, 64));
        mm = fmaxf(mm, __shfl_xor(mm, off, 64));
    }
    if ((threadIdx.x & 63) == 0) {
        atomicMax((unsigned int*)(ws + OFF_WMAX) + 0, __float_as_uint(mt));
        atomicMax((unsigned int*)(ws + OFF_WMAX) + 1, __float_as_uint(mm));
    }
}

// One block = RP unordered pairs -> 2*RP LSE outputs via +/- antisymmetry:
// row (j,i) of mma = -(row (i,j)); col (l,k) = -(col (k,l)); shift M identical
// for both signs (sweep set is sign-symmetric). Diag slots (w=0) contribute
// exp2(-M2) each to both signs, removed exactly. mma[p,p] is the same value
// for (i,j) and (j,i).
__global__ __launch_bounds__(256) void lse_kernel(float* __restrict__ ws,
                                                  float* __restrict__ out) {
    __shared__ float A[RP * NN];
    __shared__ float M2s[RP];     // M * log2e
    __shared__ float Ms[RP];      // M
    __shared__ float wred[4][2 * RP];
    __shared__ float cred[2 * RP];

    int tid = threadIdx.x, lane = tid & 63, wv = tid >> 6;
    int b = blockIdx.x;
    bool is_col = (b >= CBASE);
    const float* Mat    = ws + (is_col ? OFF_GT  : OFF_G);
    const float* wself  = ws + (is_col ? OFF_WM  : OFF_WT);
    const float* wsweep = ws + (is_col ? OFF_WST : OFF_WSM);
    float Wmax = __uint_as_float(((const unsigned int*)(ws + OFF_WMAX))[is_col ? 0 : 1]);
    int qbase = (b - (is_col ? CBASE : 0)) * RP;
    const int* tab = (const int*)ws + OFF_TAB;

    // wave wv builds A row wv for its unordered pair (i<j)
    {
        int pk = tab[qbase + wv];
        int i = pk >> 8, j = pk & 255;
        float s = INV_TEMP * wself[i * NN + j];
        const float* Mi = Mat + i * NN;
        const float* Mj = Mat + j * NN;
        float v0 = s * (Mi[lane] - Mj[lane]);
        A[wv * NN + lane] = v0;
        float vmax = v0, vmin = v0;
        if (lane < 32) {
            float v1 = s * (Mi[64 + lane] - Mj[64 + lane]);
            A[wv * NN + 64 + lane] = v1;
            vmax = fmaxf(vmax, v1); vmin = fminf(vmin, v1);
        }
        #pragma unroll
        for (int off = 32; off > 0; off >>= 1) {
            vmax = fmaxf(vmax, __shfl_xor(vmax, off, 64));
            vmin = fminf(vmin, __shfl_xor(vmin, off, 64));
        }
        if (lane == 0) {
            float M = Wmax * (vmax - vmin);   // >= max(+row) and >= max(-row)
            Ms[wv] = M;
            M2s[wv] = M * LOG2E;
        }
    }
    __syncthreads();

    int l1 = (lane < 32) ? (64 + lane) : (lane - 32);
    float M2[RP], aL1r[RP], S1p[RP], S1m[RP];
    v2f aL02[RP], S2p[RP], S2m[RP];
    #pragma unroll
    for (int r = 0; r < RP; ++r) {
        M2[r] = M2s[r];
        aL02[r].x = A[r * NN + lane];
        aL02[r].y = A[r * NN + lane + 32];
        aL1r[r] = A[r * NN + l1];
        S1p[r] = 0.f; S1m[r] = 0.f;
        S2p[r] = (v2f){0.f, 0.f};
        S2m[r] = (v2f){0.f, 0.f};
    }

    // wave wv: k-pairs idx in {wv, wv+4, ...}: (k0,k1)=(2idx,2idx+1)
    //  step0: (k0,lane)  step1: lane<32 ? (k0,64+lane) : (k1,lane-32)  step2: (k1,32+lane)
    for (int idx = wv; idx < 48; idx += 4) {
        int k0 = 2 * idx, k1 = k0 + 1;
        v2f w02;
        w02.x = wsweep[k0 * NN + lane];
        float w1 = wsweep[(lane < 32 ? k0 : k1) * NN + l1];
        w02.y = wsweep[k1 * NN + lane + 32];
        #pragma unroll
        for (int r = 0; r < RP; ++r) {
            v2f ak = *(const v2f*)&A[r * NN + k0];   // {a[k0], a[k1]}, 8B aligned
            float aksel = (lane < 32) ? ak.x : ak.y;
            v2f t02 = w02 * (ak - aL02[r]);
            v2f e, f;
            e.x = __builtin_amdgcn_exp2f(t02.x - M2[r]);
            e.y = __builtin_amdgcn_exp2f(t02.y - M2[r]);
            f.x = __builtin_amdgcn_exp2f(-t02.x - M2[r]);
            f.y = __builtin_amdgcn_exp2f(-t02.y - M2[r]);
            S2p[r] += e;
            S2m[r] += f;
            float t1 = w1 * (aksel - aL1r[r]);
            S1p[r] += __builtin_amdgcn_exp2f(t1 - M2[r]);
            S1m[r] += __builtin_amdgcn_exp2f(-t1 - M2[r]);
        }
    }

    float S[2 * RP];
    #pragma unroll
    for (int r = 0; r < RP; ++r) {
        S[r]      = S1p[r] + S2p[r].x + S2p[r].y;
        S[RP + r] = S1m[r] + S2m[r].x + S2m[r].y;
    }
    #pragma unroll
    for (int off = 32; off > 0; off >>= 1) {
        #pragma unroll
        for (int r = 0; r < 2 * RP; ++r) S[r] += __shfl_xor(S[r], off, 64);
    }
    if (lane == 0) {
        #pragma unroll
        for (int r = 0; r < 2 * RP; ++r) wred[wv][r] = S[r];
    }
    __syncthreads();

    if (tid < 2 * RP) {
        int r = tid & (RP - 1);
        float tot = wred[0][tid] + wred[1][tid] + wred[2][tid] + wred[3][tid];
        tot -= 96.f * __builtin_amdgcn_exp2f(-M2s[r]);   // remove w=0 diagonal slots
        int pk = tab[qbase + r];
        int i = pk >> 8, j = pk & 255;
        int p = i * 95 + j - 1;                          // ordered index of (i,j), j>i
        cred[tid] = Ms[r] + logf(tot) - ws[OFF_DIAG + p];
    }
    __syncthreads();
    if (tid == 0) {
        float c = 0.f;
        #pragma unroll
        for (int r = 0; r < 2 * RP; ++r) c += cred[r];
        atomicAdd(out, c * (1.0f / (float)NTASK));
    }
}

extern "C" void kernel_launch(void* const* d_in, const int* in_sizes, int n_in,
                              void* d_out, int out_size, void* d_ws, size_t ws_size,
                              hipStream_t stream) {
    const float* txt = (const float*)d_in[0];
    const float* img = (const float*)d_in[1];
    float* ws = (float*)d_ws;
    float* out = (float*)d_out;

    gram_kernel<<<dim3(6, 6, 6), 256, 0, stream>>>(txt, img, ws, out);
    pairs_kernel<<<36, 256, 0, stream>>>(ws);
    lse_kernel<<<NBLK, 256, 0, stream>>>(ws, out);
}

// Round 7
// 99.715 us; speedup vs baseline: 1.0110x; 1.0110x over previous
//
#include <hip/hip_runtime.h>
#include <math.h>

#define NN 96
#define DD 512
#define PP 9120          // NN*(NN-1) ordered pairs
#define NUP 4560         // NN*(NN-1)/2 unordered pairs
#define EPSF 1e-8f
#define INV_TEMP 100.0f
#define LOG2E 1.4426950408889634f
#define RP 4             // unordered pairs per lse block (-> 8 LSE outputs)
#define NTASK (2*PP)     // 18240 LSE outputs total
#define NBLK (2*NUP/RP)  // 2280 blocks
#define CBASE (NUP/RP)   // 1140: first block handling column tasks

typedef float v2f __attribute__((ext_vector_type(2)));

// ws float-offset layout
#define OFF_PART  0        // 6 partial grams [zz][9216], zz = z*2+kslice; z=0:G z=1:Gt z=2:Gm
#define OFF_G     55296    // G  = txt*img^T   [96*96]
#define OFF_GT    64512    // GT = G^T         [96*96]
#define OFF_WT    73728    // wt[k][l] = 1/(||t_k-t_l||+eps), diag 0
#define OFF_WM    82944
#define OFF_WST   92160    // wt * log2e
#define OFF_WSM   101376   // wm * log2e
#define OFF_DIAG  110592   // diag[p], ordered p
#define OFF_WMAX  119712   // [0]=max wt, [1]=max wm (uint bits)
#define OFF_TAB   119714   // int table: q -> (i<<8)|j, i<j, q in [0,4560)

// Split-K tiled gram: 16x16 tile over a 256-dim K slice. grid (6,6,6).
// Also zeroes WMAX and d_out (replaces memset dispatches).
__global__ __launch_bounds__(256) void gram_kernel(const float* __restrict__ txt,
                                                   const float* __restrict__ img,
                                                   float* __restrict__ ws,
                                                   float* __restrict__ out) {
    __shared__ float4 Al[16][65];
    __shared__ float4 Bl[16][65];
    if (blockIdx.x == 0 && blockIdx.y == 0 && blockIdx.z == 0 && threadIdx.x == 0) {
        ws[OFF_WMAX] = 0.f;
        ws[OFF_WMAX + 1] = 0.f;
        out[0] = 0.f;
    }
    int zz = blockIdx.z;
    int z = zz >> 1, ks = zz & 1;
    int a0 = blockIdx.x * 16, b0 = blockIdx.y * 16;
    const float* X = (z == 2) ? img : txt;
    const float* Y = (z == 0) ? img : ((z == 1) ? txt : img);
    const float4* Xp = (const float4*)X;     // row stride 128 float4
    const float4* Yp = (const float4*)Y;
    int tid = threadIdx.x;
    int r = tid >> 6, c = tid & 63;
    int kbase = ks * 64;
    #pragma unroll
    for (int rep = 0; rep < 4; ++rep) {
        int row = rep * 4 + r;
        Al[row][c] = Xp[(a0 + row) * 128 + kbase + c];
        Bl[row][c] = Yp[(b0 + row) * 128 + kbase + c];
    }
    __syncthreads();
    int al = tid >> 4, bl = tid & 15;
    float acc = 0.f;
    #pragma unroll 8
    for (int kk = 0; kk < 64; ++kk) {
        float4 av = Al[al][kk];
        float4 bv = Bl[bl][kk];
        acc += av.x*bv.x + av.y*bv.y + av.z*bv.z + av.w*bv.w;
    }
    ws[OFF_PART + zz * (NN*NN) + (a0 + al) * NN + (b0 + bl)] = acc;
}

// per (k,l): combine K-slice partials, G/GT, w grids, diag, Wmax, pair table
__global__ void pairs_kernel(float* __restrict__ ws) {
    int t = blockIdx.x * 256 + threadIdx.x;   // 36*256 = 9216 exactly
    int k = t / NN, l = t - k * NN;
    const float* P = ws + OFF_PART;
    #define RD(z, x) (P[(2*(z)) * (NN*NN) + (x)] + P[(2*(z)+1) * (NN*NN) + (x)])
    float gkl = RD(0, k*NN + l);
    float glk = RD(0, l*NN + k);
    ws[OFF_G  + t] = gkl;
    ws[OFF_GT + t] = glk;
    float wtv = 0.f, wmv = 0.f;
    if (k != l) {
        float nt2 = RD(1, k*NN+k) - 2.f*RD(1, k*NN+l) + RD(1, l*NN+l);
        float nm2 = RD(2, k*NN+k) - 2.f*RD(2, k*NN+l) + RD(2, l*NN+l);
        wtv = 1.f / (sqrtf(fmaxf(nt2, 0.f)) + EPSF);
        wmv = 1.f / (sqrtf(fmaxf(nm2, 0.f)) + EPSF);
        int p = k * 95 + l - (l > k ? 1 : 0);
        float gkk = RD(0, k*NN+k), gll = RD(0, l*NN+l);
        ws[OFF_DIAG + p] = INV_TEMP * wtv * wmv * (gkk - gkl - glk + gll);
        if (k < l) {
            int q = k * (2*NN - 1 - k) / 2 + (l - k - 1);
            ((int*)ws)[OFF_TAB + q] = (k << 8) | l;
        }
    }
    #undef RD
    ws[OFF_WT  + t] = wtv;
    ws[OFF_WM  + t] = wmv;
    ws[OFF_WST + t] = wtv * LOG2E;
    ws[OFF_WSM + t] = wmv * LOG2E;
    float mt = wtv, mm = wmv;
    #pragma unroll
    for (int off = 32; off > 0; off >>= 1) {
        mt = fmaxf(mt, __shfl_xor(mt, off, 64));
        mm = fmaxf(mm, __shfl_xor(mm, off, 64));
    }
    if ((threadIdx.x & 63) == 0) {
        atomicMax((unsigned int*)(ws + OFF_WMAX) + 0, __float_as_uint(mt));
        atomicMax((unsigned int*)(ws + OFF_WMAX) + 1, __float_as_uint(mm));
    }
}

// One block = RP unordered pairs -> 2*RP LSE outputs via +/- antisymmetry.
// Fully-unrolled 12-step sweep: all LDS reads are base+immediate, w-streams
// are pointer-walks, per-lane selects hoisted out of the loop.
__global__ __launch_bounds__(256, 4) void lse_kernel(float* __restrict__ ws,
                                                     float* __restrict__ out) {
    __shared__ __align__(16) float A[RP * NN];
    __shared__ float M2s[RP];     // M * log2e
    __shared__ float Ms[RP];      // M
    __shared__ float wred[4][2 * RP];
    __shared__ float cred[2 * RP];

    int tid = threadIdx.x, lane = tid & 63, wv = tid >> 6;
    int b = blockIdx.x;
    bool is_col = (b >= CBASE);
    const float* Mat    = ws + (is_col ? OFF_GT  : OFF_G);
    const float* wself  = ws + (is_col ? OFF_WM  : OFF_WT);
    const float* wsweep = ws + (is_col ? OFF_WST : OFF_WSM);
    float Wmax = __uint_as_float(((const unsigned int*)(ws + OFF_WMAX))[is_col ? 0 : 1]);
    int qbase = (b - (is_col ? CBASE : 0)) * RP;
    const int* tab = (const int*)ws + OFF_TAB;

    // wave wv builds A row wv for its unordered pair (i<j)
    {
        int pk = tab[qbase + wv];
        int i = pk >> 8, j = pk & 255;
        float s = INV_TEMP * wself[i * NN + j];
        const float* Mi = Mat + i * NN;
        const float* Mj = Mat + j * NN;
        float v0 = s * (Mi[lane] - Mj[lane]);
        A[wv * NN + lane] = v0;
        float vmax = v0, vmin = v0;
        if (lane < 32) {
            float v1 = s * (Mi[64 + lane] - Mj[64 + lane]);
            A[wv * NN + 64 + lane] = v1;
            vmax = fmaxf(vmax, v1); vmin = fminf(vmin, v1);
        }
        #pragma unroll
        for (int off = 32; off > 0; off >>= 1) {
            vmax = fmaxf(vmax, __shfl_xor(vmax, off, 64));
            vmin = fminf(vmin, __shfl_xor(vmin, off, 64));
        }
        if (lane == 0) {
            float M = Wmax * (vmax - vmin);   // >= max(+row) and >= max(-row)
            Ms[wv] = M;
            M2s[wv] = M * LOG2E;
        }
    }
    __syncthreads();

    // hoisted per-lane state
    int l1 = (lane < 32) ? (64 + lane) : (lane - 32);
    bool lo = (lane < 32);
    int wbase = wv * (2 * NN);                 // k0 row offset at step 0
    const float* w0p = wsweep + wbase + lane;
    const float* w1p = wsweep + wbase + l1 + (lo ? 0 : NN);
    const float* w2p = wsweep + wbase + NN + lane + 32;

    float M2[RP], aL1r[RP], S1p[RP], S1m[RP];
    v2f aL02[RP], S2p[RP], S2m[RP];
    #pragma unroll
    for (int r = 0; r < RP; ++r) {
        M2[r] = M2s[r];
        aL02[r].x = A[r * NN + lane];
        aL02[r].y = A[r * NN + lane + 32];
        aL1r[r] = A[r * NN + l1];
        S1p[r] = 0.f; S1m[r] = 0.f;
        S2p[r] = (v2f){0.f, 0.f};
        S2m[r] = (v2f){0.f, 0.f};
    }

    int kofs0 = 2 * wv;                        // LDS float offset, step-invariant part
    // fully unrolled: per step, k0 = 2*(wv + 4*step) -> LDS imm = 8*step floats,
    // w-streams advance by 8*NN floats (compile-time multiples)
    #pragma unroll
    for (int step = 0; step < 12; ++step) {
        const int wofs = step * (8 * NN);
        float w1 = w1p[wofs];
        v2f w02;
        w02.x = w0p[wofs];
        w02.y = w2p[wofs];
        #pragma unroll
        for (int r = 0; r < RP; ++r) {
            v2f ak = *(const v2f*)&A[r * NN + kofs0 + 8 * step];  // base+imm ds_read_b64
            float aksel = lo ? ak.x : ak.y;
            v2f t02 = w02 * (ak - aL02[r]);
            v2f e, f;
            e.x = __builtin_amdgcn_exp2f(t02.x - M2[r]);
            e.y = __builtin_amdgcn_exp2f(t02.y - M2[r]);
            f.x = __builtin_amdgcn_exp2f(-t02.x - M2[r]);
            f.y = __builtin_amdgcn_exp2f(-t02.y - M2[r]);
            S2p[r] += e;
            S2m[r] += f;
            float t1 = w1 * (aksel - aL1r[r]);
            S1p[r] += __builtin_amdgcn_exp2f(t1 - M2[r]);
            S1m[r] += __builtin_amdgcn_exp2f(-t1 - M2[r]);
        }
    }

    float S[2 * RP];
    #pragma unroll
    for (int r = 0; r < RP; ++r) {
        S[r]      = S1p[r] + S2p[r].x + S2p[r].y;
        S[RP + r] = S1m[r] + S2m[r].x + S2m[r].y;
    }
    #pragma unroll
    for (int off = 32; off > 0; off >>= 1) {
        #pragma unroll
        for (int r = 0; r < 2 * RP; ++r) S[r] += __shfl_xor(S[r], off, 64);
    }
    if (lane == 0) {
        #pragma unroll
        for (int r = 0; r < 2 * RP; ++r) wred[wv][r] = S[r];
    }
    __syncthreads();

    if (tid < 2 * RP) {
        int r = tid & (RP - 1);
        float tot = wred[0][tid] + wred[1][tid] + wred[2][tid] + wred[3][tid];
        tot -= 96.f * __builtin_amdgcn_exp2f(-M2s[r]);   // remove w=0 diagonal slots
        int pk = tab[qbase + r];
        int i = pk >> 8, j = pk & 255;
        int p = i * 95 + j - 1;                          // ordered index of (i,j), j>i
        cred[tid] = Ms[r] + logf(tot) - ws[OFF_DIAG + p];
    }
    __syncthreads();
    if (tid == 0) {
        float c = 0.f;
        #pragma unroll
        for (int r = 0; r < 2 * RP; ++r) c += cred[r];
        atomicAdd(out, c * (1.0f / (float)NTASK));
    }
}

extern "C" void kernel_launch(void* const* d_in, const int* in_sizes, int n_in,
                              void* d_out, int out_size, void* d_ws, size_t ws_size,
                              hipStream_t stream) {
    const float* txt = (const float*)d_in[0];
    const float* img = (const float*)d_in[1];
    float* ws = (float*)d_ws;
    float* out = (float*)d_out;

    gram_kernel<<<dim3(6, 6, 6), 256, 0, stream>>>(txt, img, ws, out);
    pairs_kernel<<<36, 256, 0, stream>>>(ws);
    lse_kernel<<<NBLK, 256, 0, stream>>>(ws, out);
}